// Round 7
// baseline (25445.132 us; speedup 1.0000x reference)
//
#include <hip/hip_runtime.h>

#define HH 1024
#define TT 4096
#define NWG 256
#define NWG_PER_LAYER 128
#define JS_PER_WG 8     // 1024 / 128
#define JS_PER_WAVE 2   // 8 j's / 4 waves
#define LDS_BYTES 131072  // 4 waves * 8 rows * 1024 floats * 4 B (w_ih tile)

__device__ __forceinline__ float fsigmoid(float x) {
    return 1.0f / (1.0f + __expf(-x));
}
__device__ __forceinline__ float ftanh(float x) {
    float ax = fabsf(x);
    float e = __expf(-2.0f * ax);
    float t = (1.0f - e) / (1.0f + e);
    return copysignf(t, x);
}
__device__ __forceinline__ void fma4(float& a, const float4 w, const float4 v) {
    a = fmaf(w.x, v.x, a);
    a = fmaf(w.y, v.y, a);
    a = fmaf(w.z, v.z, a);
    a = fmaf(w.w, v.w, a);
}

// LLC-direct (agent-coherent) 16-float load: relaxed atomic 8B loads bypass the
// (non-coherent, possibly stale) L1/L2 and read the coherence point directly.
__device__ __forceinline__ void load16_llc(float4 v[4], const float* p) {
    const unsigned long long* q = (const unsigned long long*)p;
    #pragma unroll
    for (int i = 0; i < 4; ++i) {
        unsigned long long ua = __hip_atomic_load(q + 2 * i,     __ATOMIC_RELAXED, __HIP_MEMORY_SCOPE_AGENT);
        unsigned long long ub = __hip_atomic_load(q + 2 * i + 1, __ATOMIC_RELAXED, __HIP_MEMORY_SCOPE_AGENT);
        float2 a, b;
        __builtin_memcpy(&a, &ua, 8);
        __builtin_memcpy(&b, &ub, 8);
        v[i] = make_float4(a.x, a.y, b.x, b.y);
    }
}

#define FOR_R(F) F(0) F(1) F(2) F(3) F(4) F(5) F(6) F(7)

// Persistent 2-layer LSTM, layers pipelined with skew 1.
// WGs [0,128): layer 0.  WGs [128,256): layer 1. Each wave owns 2 output rows.
// Storage (round-6 lesson: named-VGPR pinning loses to the allocator, which
// fills/spills around each asm -> w_hh lived in scratch, re-read every step):
//   w_ih: 128 KB dynamic LDS per WG, [wave][row][q][lane] (conflict-free b128)
//   w_hh + bias: AGPRs via v_accvgpr_write (136/lane) -- the AGPR class has no
//     other pressure, so the allocator cannot spill them; per-step
//     v_accvgpr_read (1 VALU op) feeds each FMA. Reads carry a loop-variant
//     dummy operand so LICM can't hoist them back into (spillable) VGPRs.
// h-vectors exchanged through LLC via relaxed agent atomics; grid sync is a
// 16x16 tree barrier with monotonic epochs; all 256 WGs co-resident (1 WG/CU).
__global__ __launch_bounds__(256, 1) void lstm2_persistent(
    const float* __restrict__ x,
    const float* __restrict__ wih0, const float* __restrict__ whh0,
    const float* __restrict__ bih0, const float* __restrict__ bhh0,
    const float* __restrict__ wih1, const float* __restrict__ whh1,
    const float* __restrict__ bih1, const float* __restrict__ bhh1,
    float* __restrict__ out,     // [T][H]  h2 (output + h2 recurrence buffer)
    float* __restrict__ ring,    // [2][H]  h1 ring (layer0 <-> layer1)
    const float* __restrict__ zbuf,   // [H] zeros (h2[-1])
    unsigned* __restrict__ leaf,      // 16 counters, 128B apart (zeroed)
    unsigned* __restrict__ root)      // 1 counter (zeroed)
{
    extern __shared__ float ldsw[];   // [4][8][4][256] floats = 128 KB

    const int wg   = blockIdx.x;
    const int tid  = threadIdx.x;
    const int wave = tid >> 6;
    const int lane = tid & 63;
    const bool isL1 = (wg >= NWG_PER_LAYER);
    const int wgl   = isL1 ? (wg - NWG_PER_LAYER) : wg;
    const int jbase = wgl * JS_PER_WG + wave * JS_PER_WAVE;
    const int col   = lane * 16;   // this lane's 16-elem chunk of the 1024-vector

    const float* wih = isL1 ? wih1 : wih0;
    const float* whh = isL1 ? whh1 : whh0;
    const float* bih = isL1 ? bih1 : bih0;
    const float* bhh = isL1 ? bhh1 : bhh0;

    // ---- stage w_ih into LDS: float offset = wave*8192 + r*1024 + q*256 + lane*4
    #pragma unroll
    for (int r = 0; r < 8; ++r) {
        const int row = (r & 3) * HH + (jbase + (r >> 2));
        const float4* p  = (const float4*)(wih + (size_t)row * HH + col);
        float*       wb = ldsw + wave * 8192 + r * 1024 + lane * 4;
        #pragma unroll
        for (int q = 0; q < 4; ++q)
            *(float4*)(wb + q * 256) = p[q];
    }

    // ---- w_hh + bias into AGPRs (un-spillable: no other AGPR pressure) ----
    #define DECLA(r) float A##r##_0, A##r##_1, A##r##_2,  A##r##_3,  A##r##_4,  A##r##_5,  A##r##_6,  A##r##_7, \
                           A##r##_8, A##r##_9, A##r##_10, A##r##_11, A##r##_12, A##r##_13, A##r##_14, A##r##_15; \
                     float AB##r;
    FOR_R(DECLA)

    #define AW(dst, s) asm volatile("v_accvgpr_write_b32 %0, %1" : "=a"(dst) : "v"(s));
    #define AWR(r) { \
        const int row = ((r) & 3) * HH + (jbase + ((r) >> 2)); \
        const float4* ph = (const float4*)(whh + (size_t)row * HH + col); \
        float4 w0 = ph[0], w1 = ph[1], w2 = ph[2], w3 = ph[3]; \
        AW(A##r##_0,  w0.x) AW(A##r##_1,  w0.y) AW(A##r##_2,  w0.z) AW(A##r##_3,  w0.w) \
        AW(A##r##_4,  w1.x) AW(A##r##_5,  w1.y) AW(A##r##_6,  w1.z) AW(A##r##_7,  w1.w) \
        AW(A##r##_8,  w2.x) AW(A##r##_9,  w2.y) AW(A##r##_10, w2.z) AW(A##r##_11, w2.w) \
        AW(A##r##_12, w3.x) AW(A##r##_13, w3.y) AW(A##r##_14, w3.z) AW(A##r##_15, w3.w) \
        float bb = bih[row] + bhh[row]; \
        AW(AB##r, bb) }
    FOR_R(AWR)

    __syncthreads();   // LDS tile ready

    float c0v = 0.0f, c1v = 0.0f;
    int loff = wave * 8192 + lane * 4;   // this lane's LDS float offset

    for (int k = 0; k <= TT; ++k) {
        asm volatile("" : "+v"(loff));   // keep LDS addressing loop-carried

        const int t = isL1 ? (k - 1) : k;
        if (t >= 0 && t < TT) {
            int kd = k;   // loop-variant dummy: blocks LICM of accvgpr reads

            // input vector: layer0 reads x[t] (plain cached); layer1 reads h1[t] (LLC)
            float4 in4[4];
            if (!isL1) {
                const float4* p = (const float4*)(x + (size_t)t * HH + col);
                in4[0] = p[0]; in4[1] = p[1]; in4[2] = p[2]; in4[3] = p[3];
            } else {
                load16_llc(in4, ring + (size_t)(t & 1) * HH + col);
            }
            // recurrent vector: layer0 -> h1[t-1] (ring), layer1 -> h2[t-1] (out)
            float4 hp4[4];
            load16_llc(hp4, isL1 ? ((t > 0) ? out + (size_t)(t - 1) * HH + col
                                            : zbuf + col)
                                 : ring + (size_t)((t - 1) & 1) * HH + col);

            float acc0, acc1, acc2, acc3, acc4, acc5, acc6, acc7;
            #define HF(r, i, hv) { float tt; \
                asm("v_accvgpr_read_b32 %0, %1" : "=v"(tt) : "a"(A##r##_##i), "v"(kd)); \
                a = fmaf(tt, hv, a); }
            #define DOTW(r) { float a = 0.0f; \
                const float4* wp = (const float4*)(ldsw + loff + (r) * 1024); \
                fma4(a, wp[0],   in4[0]); fma4(a, wp[64],  in4[1]); \
                fma4(a, wp[128], in4[2]); fma4(a, wp[192], in4[3]); \
                HF(r, 0,  hp4[0].x) HF(r, 1,  hp4[0].y) HF(r, 2,  hp4[0].z) HF(r, 3,  hp4[0].w) \
                HF(r, 4,  hp4[1].x) HF(r, 5,  hp4[1].y) HF(r, 6,  hp4[1].z) HF(r, 7,  hp4[1].w) \
                HF(r, 8,  hp4[2].x) HF(r, 9,  hp4[2].y) HF(r, 10, hp4[2].z) HF(r, 11, hp4[2].w) \
                HF(r, 12, hp4[3].x) HF(r, 13, hp4[3].y) HF(r, 14, hp4[3].z) HF(r, 15, hp4[3].w) \
                acc##r = a; }
            FOR_R(DOTW)

            // butterfly reduce all 8 accumulators across 64 lanes
            #define REDW(m) \
                acc0 += __shfl_xor(acc0, m, 64); acc1 += __shfl_xor(acc1, m, 64); \
                acc2 += __shfl_xor(acc2, m, 64); acc3 += __shfl_xor(acc3, m, 64); \
                acc4 += __shfl_xor(acc4, m, 64); acc5 += __shfl_xor(acc5, m, 64); \
                acc6 += __shfl_xor(acc6, m, 64); acc7 += __shfl_xor(acc7, m, 64);
            REDW(1) REDW(2) REDW(4) REDW(8) REDW(16) REDW(32)

            // bias from AGPRs
            #define BR(r, dst) float dst; \
                asm("v_accvgpr_read_b32 %0, %1" : "=v"(dst) : "a"(AB##r), "v"(kd));
            BR(0, b0) BR(1, b1) BR(2, b2) BR(3, b3)
            BR(4, b4) BR(5, b5) BR(6, b6) BR(7, b7)

            // gates (PyTorch order i,f,g,o)
            const float gi0 = fsigmoid(acc0 + b0), gf0 = fsigmoid(acc1 + b1);
            const float gg0 = ftanh(acc2 + b2),    go0 = fsigmoid(acc3 + b3);
            c0v = gf0 * c0v + gi0 * gg0;
            const float h0 = go0 * ftanh(c0v);
            const float gi1 = fsigmoid(acc4 + b4), gf1 = fsigmoid(acc5 + b5);
            const float gg1 = ftanh(acc6 + b6),    go1 = fsigmoid(acc7 + b7);
            c1v = gf1 * c1v + gi1 * gg1;
            const float h1v = go1 * ftanh(c1v);

            if (lane == 0) {
                float2 hv = make_float2(h0, h1v);   // jbase, jbase+1 (jbase even)
                unsigned long long bits;
                __builtin_memcpy(&bits, &hv, 8);
                float* dstf = isL1 ? (out  + (size_t)t * HH + jbase)
                                   : (ring + (size_t)(t & 1) * HH + jbase);
                __hip_atomic_store((unsigned long long*)dstf, bits,
                                   __ATOMIC_RELAXED, __HIP_MEMORY_SCOPE_AGENT);
            }
        }

        // ---- tree grid barrier (monotonic epochs, no L2 flushes) ----
        if (k < TT) {
            __syncthreads();   // each wave drains its own vmcnt before s_barrier
            if (tid == 0) {
                asm volatile("s_waitcnt vmcnt(0)" ::: "memory");  // h at LLC
                unsigned old = __hip_atomic_fetch_add(&leaf[(wg >> 4) * 32], 1u,
                                   __ATOMIC_RELAXED, __HIP_MEMORY_SCOPE_AGENT);
                if (old == (unsigned)(k * 16 + 15))   // last of 16 WGs in leaf
                    __hip_atomic_fetch_add(root, 1u,
                                   __ATOMIC_RELAXED, __HIP_MEMORY_SCOPE_AGENT);
                const unsigned tgt = (unsigned)((k + 1) * 16);
                while (__hip_atomic_load(root, __ATOMIC_RELAXED,
                                         __HIP_MEMORY_SCOPE_AGENT) < tgt)
                    __builtin_amdgcn_s_sleep(1);
            }
            __syncthreads();
        }
    }
}

extern "C" void kernel_launch(void* const* d_in, const int* in_sizes, int n_in,
                              void* d_out, int out_size, void* d_ws, size_t ws_size,
                              hipStream_t stream) {
    (void)in_sizes; (void)n_in; (void)out_size; (void)ws_size;
    const float* x    = (const float*)d_in[0];
    const float* wih0 = (const float*)d_in[1];
    const float* whh0 = (const float*)d_in[2];
    const float* bih0 = (const float*)d_in[3];
    const float* bhh0 = (const float*)d_in[4];
    const float* wih1 = (const float*)d_in[5];
    const float* whh1 = (const float*)d_in[6];
    const float* bih1 = (const float*)d_in[7];
    const float* bhh1 = (const float*)d_in[8];
    float* out = (float*)d_out;

    // ws layout: [0,2048) leaf counters (16 x 128B) | [2048,2176) root |
    //            [4096,8192) zbuf | [8192,16384) ring
    unsigned* leaf = (unsigned*)d_ws;
    unsigned* root = (unsigned*)((char*)d_ws + 2048);
    float*    zbuf = (float*)((char*)d_ws + 4096);
    float*    ring = (float*)((char*)d_ws + 8192);

    // allow 128 KB dynamic LDS (160 KB available per CU on gfx950)
    hipFuncSetAttribute((const void*)lstm2_persistent,
                        hipFuncAttributeMaxDynamicSharedMemorySize, LDS_BYTES);

    // zero counters + zbuf + ring every call (stream-ordered, graph-capturable)
    hipMemsetAsync(d_ws, 0, 16384, stream);

    hipLaunchKernelGGL(lstm2_persistent, dim3(NWG), dim3(256), LDS_BYTES, stream,
                       x, wih0, whh0, bih0, bhh0,
                       wih1, whh1, bih1, bhh1, out, ring, zbuf, leaf, root);
}